// Round 10
// baseline (310.701 us; speedup 1.0000x reference)
//
#include <hip/hip_runtime.h>
#include <hip/hip_bf16.h>
#include <math.h>

#define Bc 8
#define Tc 8192
#define NTOK 256
#define Dc 512
#define TXT 768
#define TEc 2048
#define Hc 8
#define DHc 64
#define MROWS (Bc * Tc)   // 65536

typedef __attribute__((ext_vector_type(8))) short bf16x8v;
typedef __attribute__((ext_vector_type(8))) unsigned short u16x8;
typedef __attribute__((ext_vector_type(4))) unsigned short u16x4;
typedef __attribute__((ext_vector_type(4))) float f32x4;

#define MFMA16(a, b, c) __builtin_amdgcn_mfma_f32_16x16x32_bf16(a, b, c, 0, 0, 0)

__device__ __forceinline__ unsigned short f2bf(float f) {
    __hip_bfloat16 h = __float2bfloat16(f);
    return __builtin_bit_cast(unsigned short, h);
}
__device__ __forceinline__ float bf2f(unsigned short u) {
    unsigned int x = ((unsigned int)u) << 16;
    return __builtin_bit_cast(float, x);
}

typedef __attribute__((address_space(3))) unsigned int lds_u32_t;
typedef __attribute__((address_space(1))) const unsigned int gbl_u32_t;
__device__ __forceinline__ void gload16(const unsigned short* g, short* l) {
    __builtin_amdgcn_global_load_lds((gbl_u32_t*)g, (lds_u32_t*)l, 16, 0, 0);
}

// ---------------------------------------------------------------------------
// prep: 4 weight transposes (f32 -> bf16 [n][k]) + ln_t, one launch
// ---------------------------------------------------------------------------
__device__ __forceinline__ void transpose_tile(const float* __restrict__ src,
                                               unsigned short* __restrict__ dst,
                                               int N, int rs, int k0, int n0) {
    __shared__ float tile[64][65];
    int tx = threadIdx.x & 63, tq = threadIdx.x >> 6;
#pragma unroll
    for (int i = 0; i < 16; ++i) {
        int kk = tq + i * 4;
        tile[kk][tx] = src[(size_t)(k0 + kk) * N + n0 + tx];
    }
    __syncthreads();
#pragma unroll
    for (int i = 0; i < 16; ++i) {
        int nn = tq + i * 4;
        dst[(size_t)(n0 + nn) * rs + k0 + tx] = f2bf(tile[tx][nn]);
    }
}

__global__ void __launch_bounds__(256) prep_kernel(
    const float* __restrict__ Wq, const float* __restrict__ oW,
    const float* __restrict__ Wk, const float* __restrict__ Wv,
    const float* __restrict__ xf, const float* __restrict__ ln_t_g,
    const float* __restrict__ ln_t_b,
    unsigned short* __restrict__ Wqt, unsigned short* __restrict__ oWt,
    unsigned short* __restrict__ Wkvt, unsigned short* __restrict__ xt) {
    int bid = blockIdx.x;
    if (bid < 64) {
        transpose_tile(Wq, Wqt, Dc, Dc, (bid >> 3) * 64, (bid & 7) * 64);
        return;
    }
    if (bid < 128) {
        int i = bid - 64;
        transpose_tile(oW, oWt, Dc, Dc, (i >> 3) * 64, (i & 7) * 64);
        return;
    }
    if (bid < 224) {
        int i = bid - 128;
        transpose_tile(Wk, Wkvt, Dc, TXT, (i >> 3) * 64, (i & 7) * 64);
        return;
    }
    if (bid < 320) {
        int i = bid - 224;
        transpose_tile(Wv, Wkvt + (size_t)512 * TXT, Dc, TXT, (i >> 3) * 64, (i & 7) * 64);
        return;
    }
    int w = threadIdx.x >> 6, l = threadIdx.x & 63;
    int row = (bid - 320) * 4 + w;
    const float* src = xf + (size_t)row * TXT;
    float4 a0 = *(const float4*)&src[l * 12];
    float4 a1 = *(const float4*)&src[l * 12 + 4];
    float4 a2 = *(const float4*)&src[l * 12 + 8];
    float vals[12] = {a0.x, a0.y, a0.z, a0.w, a1.x, a1.y, a1.z, a1.w,
                      a2.x, a2.y, a2.z, a2.w};
    float s = 0.f, ss = 0.f;
#pragma unroll
    for (int j = 0; j < 12; ++j) { s += vals[j]; ss += vals[j] * vals[j]; }
#pragma unroll
    for (int m = 1; m <= 32; m <<= 1) { s += __shfl_xor(s, m); ss += __shfl_xor(ss, m); }
    float mean = s * (1.f / TXT), var = ss * (1.f / TXT) - mean * mean;
    float rs = rsqrtf(var + 1e-5f);
    unsigned short o[12];
#pragma unroll
    for (int j = 0; j < 12; ++j) {
        int c = l * 12 + j;
        o[j] = f2bf((vals[j] - mean) * rs * ln_t_g[c] + ln_t_b[c]);
    }
    unsigned short* dp = xt + (size_t)row * TXT + l * 12;
    *(u16x4*)&dp[0] = *(u16x4*)&o[0];
    *(u16x4*)&dp[4] = *(u16x4*)&o[4];
    *(u16x4*)&dp[8] = *(u16x4*)&o[8];
}

// ---------------------------------------------------------------------------
// kvgemm: [2048x768] @ [768x1024] -> k (softmaxed) | v  (r3-proven)
// ---------------------------------------------------------------------------
__global__ void __launch_bounds__(256) kvgemm_kernel(
    const unsigned short* __restrict__ xt, const unsigned short* __restrict__ Wkvt,
    const float* __restrict__ bk, const float* __restrict__ bv,
    unsigned short* __restrict__ kbuf, unsigned short* __restrict__ vbuf) {
    __shared__ short lds_s[16384];
    short* Alds = lds_s;
    short* Blds = lds_s + 8192;

    const int tid = threadIdx.x, l = tid & 63, w = tid >> 6;
    const int lr = l & 15, lg = l >> 4;
    int mt = blockIdx.x >> 3, nt = blockIdx.x & 7;
    int row0 = mt * 128, col0 = nt * 128;
    int wrow = (w >> 1) * 64, wcol = (w & 1) * 64;

    f32x4 acc[4][4] = {};
    const int cbase = w * 64 + l;

    for (int ks = 0; ks < 12; ++ks) {
#pragma unroll
        for (int i = 0; i < 4; ++i) {
            int c = i * 256 + cbase;
            int r = c >> 3, kc = c & 7;
            int koff = ks * 64 + ((kc ^ (r & 7)) << 3);
            gload16(xt + (size_t)(row0 + r) * TXT + koff, &Alds[((i * 4 + w) * 64) * 8]);
            gload16(Wkvt + (size_t)(col0 + r) * TXT + koff, &Blds[((i * 4 + w) * 64) * 8]);
        }
        __syncthreads();
#pragma unroll
        for (int kk = 0; kk < 2; ++kk) {
            int kcw = kk * 4 + lg;
            bf16x8v af[4], bfr[4];
#pragma unroll
            for (int i = 0; i < 4; ++i) {
                int r = wrow + i * 16 + lr;
                af[i] = *(bf16x8v*)&Alds[(r * 8 + (kcw ^ (r & 7))) * 8];
            }
#pragma unroll
            for (int j = 0; j < 4; ++j) {
                int n = wcol + j * 16 + lr;
                bfr[j] = *(bf16x8v*)&Blds[(n * 8 + (kcw ^ (n & 7))) * 8];
            }
#pragma unroll
            for (int i = 0; i < 4; ++i)
#pragma unroll
                for (int j = 0; j < 4; ++j)
                    acc[i][j] = MFMA16(af[i], bfr[j], acc[i][j]);
        }
        __syncthreads();
    }

    const bool kHalf = (col0 + wcol) < 512;
    int cj[4];
    float bias[4];
#pragma unroll
    for (int j = 0; j < 4; ++j) {
        cj[j] = col0 + wcol + j * 16 + lr;
        bias[j] = kHalf ? bk[cj[j]] : bv[cj[j] - 512];
    }
#pragma unroll
    for (int i = 0; i < 4; ++i)
#pragma unroll
        for (int reg = 0; reg < 4; ++reg) {
            float v0 = acc[i][0][reg] + bias[0], v1 = acc[i][1][reg] + bias[1];
            float v2 = acc[i][2][reg] + bias[2], v3 = acc[i][3][reg] + bias[3];
            if (kHalf) {
                float m = fmaxf(fmaxf(v0, v1), fmaxf(v2, v3));
                m = fmaxf(m, __shfl_xor(m, 1)); m = fmaxf(m, __shfl_xor(m, 2));
                m = fmaxf(m, __shfl_xor(m, 4)); m = fmaxf(m, __shfl_xor(m, 8));
                float e0 = __expf(v0 - m), e1 = __expf(v1 - m);
                float e2 = __expf(v2 - m), e3 = __expf(v3 - m);
                float ssum = e0 + e1 + e2 + e3;
                ssum += __shfl_xor(ssum, 1); ssum += __shfl_xor(ssum, 2);
                ssum += __shfl_xor(ssum, 4); ssum += __shfl_xor(ssum, 8);
                float inv = 1.f / ssum;
                v0 = e0 * inv; v1 = e1 * inv; v2 = e2 * inv; v3 = e3 * inv;
            }
            int r = row0 + wrow + i * 16 + 4 * lg + reg;
            float vv[4] = {v0, v1, v2, v3};
#pragma unroll
            for (int j = 0; j < 4; ++j) {
                if (kHalf) kbuf[(size_t)r * Dc + cj[j]] = f2bf(vv[j]);
                else       vbuf[(size_t)r * Dc + cj[j] - 512] = f2bf(vv[j]);
            }
        }
}

// ---------------------------------------------------------------------------
// attn: attn_t[b,h][l][d] = sum_n k[b,n,h,d]*v[b,n,h,l]
// ---------------------------------------------------------------------------
__global__ void __launch_bounds__(512) attn_kernel(const unsigned short* __restrict__ kbuf,
                                                   const unsigned short* __restrict__ vbuf,
                                                   unsigned short* __restrict__ attn_t) {
    __shared__ unsigned short ksh[128][DHc], vsh[128][DHc];
    const int tid = threadIdx.x;
    const int b = blockIdx.x >> 3, h = blockIdx.x & 7;
    const int d = tid >> 3, lb = (tid & 7) * 8;
    const int tok = tid >> 2, c0 = (tid & 3) * 16;
    float acc[8] = {0.f};
    for (int st = 0; st < 2; ++st) {
        __syncthreads();
        size_t o = (size_t)(b * NTOK + st * 128 + tok) * Dc + h * DHc + c0;
        *(u16x8*)&ksh[tok][c0]     = *(const u16x8*)&kbuf[o];
        *(u16x8*)&ksh[tok][c0 + 8] = *(const u16x8*)&kbuf[o + 8];
        *(u16x8*)&vsh[tok][c0]     = *(const u16x8*)&vbuf[o];
        *(u16x8*)&vsh[tok][c0 + 8] = *(const u16x8*)&vbuf[o + 8];
        __syncthreads();
        for (int n = 0; n < 128; ++n) {
            float kd = bf2f(ksh[n][d]);
            u16x4 va = *(const u16x4*)&vsh[n][lb];
            u16x4 vb = *(const u16x4*)&vsh[n][lb + 4];
#pragma unroll
            for (int e = 0; e < 4; ++e) acc[e] += kd * bf2f(va[e]);
#pragma unroll
            for (int e = 0; e < 4; ++e) acc[4 + e] += kd * bf2f(vb[e]);
        }
    }
    size_t base = (size_t)(b * 8 + h) * DHc * DHc;
#pragma unroll
    for (int e = 0; e < 8; ++e)
        attn_t[base + (size_t)(lb + e) * DHc + d] = f2bf(acc[e]);
}

// ---------------------------------------------------------------------------
// emb: eo[b,:] = silu(emb[b]) @ emb_W + emb_b
// ---------------------------------------------------------------------------
__global__ void __launch_bounds__(256) emb_kernel(const float* __restrict__ emb,
                                                  const float* __restrict__ emb_W,
                                                  const float* __restrict__ emb_b,
                                                  float* __restrict__ eo) {
    __shared__ float s[4][TEc];
    __shared__ float red[4][64][4];
    const int tid = threadIdx.x;
    const int chunk = blockIdx.x >> 1, bh = blockIdx.x & 1;
#pragma unroll
    for (int j = 0; j < 8; ++j) {
        int idx = tid + 256 * j;
        int bi = idx >> 9, kk4 = (idx & 511) * 4;
#pragma unroll
        for (int e = 0; e < 4; ++e) {
            float v = emb[(bh * 4 + bi) * TEc + kk4 + e];
            s[bi][kk4 + e] = v / (1.f + __expf(-v));
        }
    }
    __syncthreads();
    int c = tid & 63, q = tid >> 6;
    int col = chunk * 64 + c;
    float acc[4] = {0.f, 0.f, 0.f, 0.f};
    for (int kk = q * 512; kk < q * 512 + 512; ++kk) {
        float wv = emb_W[(size_t)kk * (2 * Dc) + col];
#pragma unroll
        for (int bi = 0; bi < 4; ++bi) acc[bi] += s[bi][kk] * wv;
    }
#pragma unroll
    for (int bi = 0; bi < 4; ++bi) red[q][c][bi] = acc[bi];
    __syncthreads();
    if (q == 0) {
        float bb = emb_b[col];
#pragma unroll
        for (int bi = 0; bi < 4; ++bi)
            eo[(bh * 4 + bi) * (2 * Dc) + col] =
                red[0][c][bi] + red[1][c][bi] + red[2][c][bi] + red[3][c][bi] + bb;
    }
}

// ---------------------------------------------------------------------------
// gemm1m: BM=64, BN=512, BK=64, 512 thr (8 waves, 1M x 8N; wave = one head).
// Fuses: LN(x) in-reg -> A via masked ds_write; GEMM + bq + head-softmax;
// q @ attn_t; cross-wave row-LN + FiLM + SiLU -> A2 (bf16).
// LDS: A [64][64] 8KB + B [512][64] 64KB = 72KB. pstat overlays A; Qw in B.
// ---------------------------------------------------------------------------
__global__ void __launch_bounds__(512, 4) gemm1m_kernel(
    const float* __restrict__ x, const float* __restrict__ lng,
    const float* __restrict__ lnb, const unsigned short* __restrict__ Wt,
    const float* __restrict__ bq, const unsigned short* __restrict__ attn_t,
    const float* __restrict__ eo, const float* __restrict__ go_,
    const float* __restrict__ bo_, unsigned short* __restrict__ A2) {
    __shared__ short lds_s[36864];            // 72 KB
    short* Alds = lds_s;                      // 4096 shorts = [64][64] swizzled
    short* Blds = lds_s + 4096;               // 32768 shorts = [512][64] swizzled

    const int tid = threadIdx.x, l = tid & 63, w = tid >> 6;
    const int lr = l & 15, lg = l >> 4;
    const int row0 = blockIdx.x * 64;
    const int b = row0 >> 13;
    const int wcol = w * 64;                  // wave = head w

    // ---- LN(x) pre-pass: 8 rows per wave, values kept in registers
    bf16x8v xr[8];
    {
        float4 g0 = *(const float4*)&lng[l * 8], g1 = *(const float4*)&lng[l * 8 + 4];
        float4 b0 = *(const float4*)&lnb[l * 8], b1 = *(const float4*)&lnb[l * 8 + 4];
        float gg[8] = {g0.x, g0.y, g0.z, g0.w, g1.x, g1.y, g1.z, g1.w};
        float bb[8] = {b0.x, b0.y, b0.z, b0.w, b1.x, b1.y, b1.z, b1.w};
#pragma unroll
        for (int rr = 0; rr < 8; ++rr) {
            const float* src = x + (size_t)(row0 + w * 8 + rr) * Dc + l * 8;
            float4 a0 = *(const float4*)&src[0];
            float4 a1 = *(const float4*)&src[4];
            float vals[8] = {a0.x, a0.y, a0.z, a0.w, a1.x, a1.y, a1.z, a1.w};
            float s = 0.f, ss = 0.f;
#pragma unroll
            for (int j = 0; j < 8; ++j) { s += vals[j]; ss += vals[j] * vals[j]; }
#pragma unroll
            for (int m = 1; m <= 32; m <<= 1) { s += __shfl_xor(s, m); ss += __shfl_xor(ss, m); }
            float mean = s * (1.f / Dc), var = ss * (1.f / Dc) - mean * mean;
            float rsq = rsqrtf(var + 1e-5f);
#pragma unroll
            for (int j = 0; j < 8; ++j)
                xr[rr][j] = (short)f2bf((vals[j] - mean) * rsq * gg[j] + bb[j]);
        }
    }

    f32x4 acc[4][4] = {};

    for (int ks = 0; ks < 8; ++ks) {
        // A-tile: lanes holding this K-step's cols ds_write their 8 rows
        if ((l >> 3) == ks) {
            int kc = l & 7;
#pragma unroll
            for (int rr = 0; rr < 8; ++rr) {
                int r = w * 8 + rr;
                *(bf16x8v*)&Alds[(r * 8 + (kc ^ (r & 7))) * 8] = xr[rr];
            }
        }
        // B-tile: 512 rows x 64 k via gload16 (8 rounds)
#pragma unroll
        for (int i = 0; i < 8; ++i) {
            int c = i * 512 + tid;
            int r = c >> 3, kc = c & 7;
            int koff = ks * 64 + ((kc ^ (r & 7)) << 3);
            gload16(Wt + (size_t)r * Dc + koff, &Blds[((i * 8 + w) * 64) * 8]);
        }
        __syncthreads();
#pragma unroll
        for (int kk = 0; kk < 2; ++kk) {
            int kcw = kk * 4 + lg;
            bf16x8v af[4], bfr[4];
#pragma unroll
            for (int i = 0; i < 4; ++i) {
                int r = i * 16 + lr;
                af[i] = *(bf16x8v*)&Alds[(r * 8 + (kcw ^ (r & 7))) * 8];
            }
#pragma unroll
            for (int j = 0; j < 4; ++j) {
                int n = wcol + j * 16 + lr;
                bfr[j] = *(bf16x8v*)&Blds[(n * 8 + (kcw ^ (n & 7))) * 8];
            }
#pragma unroll
            for (int i = 0; i < 4; ++i)
#pragma unroll
                for (int j = 0; j < 4; ++j)
                    acc[i][j] = MFMA16(af[i], bfr[j], acc[i][j]);
        }
        __syncthreads();
    }

    // ---- bias + per-(row,head) softmax + PV (head = wave)
    float bqv[4];
#pragma unroll
    for (int j = 0; j < 4; ++j) bqv[j] = bq[wcol + j * 16 + lr];
    const unsigned short* at = attn_t + (size_t)(b * 8 + w) * DHc * DHc;
    short* Qw = Blds + w * 1024;               // per-wave 16x64 scratch (B dead)

#pragma unroll
    for (int i = 0; i < 4; ++i) {
#pragma unroll
        for (int reg = 0; reg < 4; ++reg) {
            float v0 = acc[i][0][reg] + bqv[0], v1 = acc[i][1][reg] + bqv[1];
            float v2 = acc[i][2][reg] + bqv[2], v3 = acc[i][3][reg] + bqv[3];
            float m = fmaxf(fmaxf(v0, v1), fmaxf(v2, v3));
            m = fmaxf(m, __shfl_xor(m, 1)); m = fmaxf(m, __shfl_xor(m, 2));
            m = fmaxf(m, __shfl_xor(m, 4)); m = fmaxf(m, __shfl_xor(m, 8));
            float e0 = __expf(v0 - m), e1 = __expf(v1 - m);
            float e2 = __expf(v2 - m), e3 = __expf(v3 - m);
            float ssum = e0 + e1 + e2 + e3;
            ssum += __shfl_xor(ssum, 1); ssum += __shfl_xor(ssum, 2);
            ssum += __shfl_xor(ssum, 4); ssum += __shfl_xor(ssum, 8);
            float inv = 1.f / ssum;
            acc[i][0][reg] = e0 * inv; acc[i][1][reg] = e1 * inv;
            acc[i][2][reg] = e2 * inv; acc[i][3][reg] = e3 * inv;
        }
#pragma unroll
        for (int j = 0; j < 4; ++j)
#pragma unroll
            for (int reg = 0; reg < 4; ++reg) {
                int rl = 4 * lg + reg;
                int c = j * 16 + lr;
                Qw[(rl * 8 + ((c >> 3) ^ (rl & 7))) * 8 + (c & 7)] =
                    (short)f2bf(acc[i][j][reg]);
            }
        f32x4 acc2[4] = {};
#pragma unroll
        for (int kk = 0; kk < 2; ++kk) {
            int kc = kk * 4 + lg;
            bf16x8v a = *(bf16x8v*)&Qw[(lr * 8 + (kc ^ (lr & 7))) * 8];
            bf16x8v bf2[4];
#pragma unroll
            for (int j = 0; j < 4; ++j)
                bf2[j] = *(const bf16x8v*)&at[(j * 16 + lr) * DHc + kk * 32 + lg * 8];
#pragma unroll
            for (int j = 0; j < 4; ++j)
                acc2[j] = MFMA16(a, bf2[j], acc2[j]);
        }
#pragma unroll
        for (int j = 0; j < 4; ++j) acc[i][j] = acc2[j];   // acc := out1 values
    }

    // ---- cross-wave row stats (LN over 512 cols), pstat overlays Alds
    float* pstat = (float*)Alds;               // [64 rows][8 waves][2]
#pragma unroll
    for (int i = 0; i < 4; ++i)
#pragma unroll
        for (int reg = 0; reg < 4; ++reg) {
            float s = acc[i][0][reg] + acc[i][1][reg] + acc[i][2][reg] + acc[i][3][reg];
            float ss = acc[i][0][reg] * acc[i][0][reg] + acc[i][1][reg] * acc[i][1][reg]
                     + acc[i][2][reg] * acc[i][2][reg] + acc[i][3][reg] * acc[i][3][reg];
            s += __shfl_xor(s, 1); ss += __shfl_xor(ss, 1);
            s += __shfl_xor(s, 2); ss += __shfl_xor(ss, 2);
            s += __shfl_xor(s, 4); ss += __shfl_xor(ss, 4);
            s += __shfl_xor(s, 8); ss += __shfl_xor(ss, 8);
            if (lr == 0) {
                int rloc = i * 16 + 4 * lg + reg;
                pstat[(rloc * 8 + w) * 2 + 0] = s;
                pstat[(rloc * 8 + w) * 2 + 1] = ss;
            }
        }
    __syncthreads();

    // ---- combine stats, FiLM + SiLU, store A2
    const float* scl = eo + (size_t)b * (2 * Dc);
    const float* shf = scl + Dc;
    float go[4], bo[4], sc[4], sh[4];
#pragma unroll
    for (int j = 0; j < 4; ++j) {
        int c = wcol + j * 16 + lr;
        go[j] = go_[c]; bo[j] = bo_[c]; sc[j] = scl[c]; sh[j] = shf[c];
    }
#pragma unroll
    for (int i = 0; i < 4; ++i)
#pragma unroll
        for (int reg = 0; reg < 4; ++reg) {
            int rloc = i * 16 + 4 * lg + reg;
            float s = 0.f, ss = 0.f;
#pragma unroll
            for (int q = 0; q < 8; ++q) {
                s += pstat[(rloc * 8 + q) * 2 + 0];
                ss += pstat[(rloc * 8 + q) * 2 + 1];
            }
            float mean = s * (1.f / Dc), var = ss * (1.f / Dc) - mean * mean;
            float rsq = rsqrtf(var + 1e-5f);
            size_t rowoff = (size_t)(row0 + rloc) * Dc;
#pragma unroll
            for (int j = 0; j < 4; ++j) {
                float t = (acc[i][j][reg] - mean) * rsq * go[j] + bo[j];
                t = t * (1.f + sc[j]) + sh[j];
                t = t / (1.f + __expf(-t));
                A2[rowoff + wcol + j * 16 + lr] = f2bf(t);
            }
        }
}

// ---------------------------------------------------------------------------
// gemm2: BM=256, BN=128, BK=64, 512 thr (r5-proven). out = x + A2 @ oWt + ob
// ---------------------------------------------------------------------------
__global__ void __launch_bounds__(512, 4) gemm2_kernel(
    const unsigned short* __restrict__ A2, const unsigned short* __restrict__ Wt,
    const float* __restrict__ ob, const float* __restrict__ x,
    float* __restrict__ out) {
    __shared__ short lds_s[24576];
    short* Alds = lds_s;
    short* Blds = lds_s + 16384;

    const int tid = threadIdx.x, l = tid & 63, w = tid >> 6;
    const int lr = l & 15, lg = l >> 4;
    int raw = blockIdx.x;
    int swz = (raw & 7) * 128 + (raw >> 3);
    int mt = swz >> 2, nt = swz & 3;
    int row0 = mt * 256, col0 = nt * 128;
    int wrow = (w >> 1) * 64, wcol = (w & 1) * 64;

    f32x4 acc[4][4] = {};

    for (int ks = 0; ks < 8; ++ks) {
#pragma unroll
        for (int i = 0; i < 4; ++i) {
            int c = i * 512 + tid;
            int r = c >> 3, kc = c & 7;
            int koff = ks * 64 + ((kc ^ (r & 7)) << 3);
            gload16(A2 + (size_t)(row0 + r) * Dc + koff, &Alds[(i * 8 + w) * 512]);
        }
#pragma unroll
        for (int i = 0; i < 2; ++i) {
            int c = i * 512 + tid;
            int r = c >> 3, kc = c & 7;
            int koff = ks * 64 + ((kc ^ (r & 7)) << 3);
            gload16(Wt + (size_t)(col0 + r) * Dc + koff, &Blds[(i * 8 + w) * 512]);
        }
        __syncthreads();
#pragma unroll
        for (int kk = 0; kk < 2; ++kk) {
            int kcw = kk * 4 + lg;
            bf16x8v af[4], bfr[4];
#pragma unroll
            for (int i = 0; i < 4; ++i) {
                int r = wrow + i * 16 + lr;
                af[i] = *(bf16x8v*)&Alds[(r * 8 + (kcw ^ (r & 7))) * 8];
            }
#pragma unroll
            for (int j = 0; j < 4; ++j) {
                int n = wcol + j * 16 + lr;
                bfr[j] = *(bf16x8v*)&Blds[(n * 8 + (kcw ^ (n & 7))) * 8];
            }
#pragma unroll
            for (int i = 0; i < 4; ++i)
#pragma unroll
                for (int j = 0; j < 4; ++j)
                    acc[i][j] = MFMA16(af[i], bfr[j], acc[i][j]);
        }
        __syncthreads();
    }

    float obv[4];
#pragma unroll
    for (int j = 0; j < 4; ++j) obv[j] = ob[col0 + wcol + j * 16 + lr];
#pragma unroll
    for (int i = 0; i < 4; ++i)
#pragma unroll
        for (int j = 0; j < 4; ++j)
#pragma unroll
            for (int reg = 0; reg < 4; ++reg) {
                int r = row0 + wrow + i * 16 + 4 * lg + reg;
                int c = col0 + wcol + j * 16 + lr;
                size_t o = (size_t)r * Dc + c;
                out[o] = acc[i][j][reg] + obv[j] + x[o];
            }
}

// ---------------------------------------------------------------------------
extern "C" void kernel_launch(void* const* d_in, const int* in_sizes, int n_in,
                              void* d_out, int out_size, void* d_ws, size_t ws_size,
                              hipStream_t stream) {
    const float* x      = (const float*)d_in[0];
    const float* xf     = (const float*)d_in[1];
    const float* emb    = (const float*)d_in[2];
    const float* ln_x_g = (const float*)d_in[3];
    const float* ln_x_b = (const float*)d_in[4];
    const float* ln_t_g = (const float*)d_in[5];
    const float* ln_t_b = (const float*)d_in[6];
    const float* Wq     = (const float*)d_in[7];
    const float* bq     = (const float*)d_in[8];
    const float* Wk     = (const float*)d_in[9];
    const float* bk     = (const float*)d_in[10];
    const float* Wv     = (const float*)d_in[11];
    const float* bv     = (const float*)d_in[12];
    const float* emb_W  = (const float*)d_in[13];
    const float* emb_b  = (const float*)d_in[14];
    const float* ln_o_g = (const float*)d_in[15];
    const float* ln_o_b = (const float*)d_in[16];
    const float* out_W  = (const float*)d_in[17];
    const float* out_b  = (const float*)d_in[18];
    float* out = (float*)d_out;

    // ws layout (u16 units unless noted)
    unsigned short* xt   = (unsigned short*)d_ws;                 // 2048*768
    unsigned short* kbuf = xt + (size_t)2048 * TXT;               // 2048*512
    unsigned short* vbuf = kbuf + (size_t)2048 * 512;             // 2048*512
    unsigned short* Wkvt = vbuf + (size_t)2048 * 512;             // 1024*768
    unsigned short* Wqt  = Wkvt + (size_t)1024 * TXT;             // 512*512
    unsigned short* oWt  = Wqt + (size_t)512 * 512;               // 512*512
    unsigned short* attn_t = oWt + (size_t)512 * 512;             // 64*64*64
    float* eo = (float*)(attn_t + (size_t)64 * 64 * 64);          // 8*1024 f32
    unsigned short* A2 = (unsigned short*)(eo + 8 * 1024);        // 65536*512

    hipLaunchKernelGGL(prep_kernel, dim3(832), dim3(256), 0, stream,
                       Wq, out_W, Wk, Wv, xf, ln_t_g, ln_t_b, Wqt, oWt, Wkvt, xt);
    hipLaunchKernelGGL(kvgemm_kernel, dim3(16 * 8), dim3(256), 0, stream,
                       xt, Wkvt, bk, bv, kbuf, vbuf);
    hipLaunchKernelGGL(attn_kernel, dim3(Bc * Hc), dim3(512), 0, stream,
                       kbuf, vbuf, attn_t);
    hipLaunchKernelGGL(emb_kernel, dim3(32), dim3(256), 0, stream, emb, emb_W, emb_b, eo);
    hipLaunchKernelGGL(gemm1m_kernel, dim3(MROWS / 64), dim3(512), 0, stream,
                       x, ln_x_g, ln_x_b, Wqt, bq, attn_t, eo, ln_o_g, ln_o_b, A2);
    hipLaunchKernelGGL(gemm2_kernel, dim3(MROWS / 256 * 4), dim3(512), 0, stream,
                       A2, oWt, out_b, x, out);
}